// Round 1
// baseline (1804.353 us; speedup 1.0000x reference)
//
#include <hip/hip_runtime.h>
#include <hip/hip_bf16.h>

#define NN 100000
#define NE 1600000
#define HID 64

// ---------------- degree (once per call) ----------------
__global__ void deg_kernel(const int* __restrict__ dst, float* __restrict__ deg, int nE) {
    int e = blockIdx.x * blockDim.x + threadIdx.x;
    if (e < nE) atomicAdd(&deg[dst[e]], 1.0f);
}

// ---------------- scatter-add: agg[dst] += h[src] ----------------
template <int F>
__global__ void scatter_kernel(const int* __restrict__ src, const int* __restrict__ dst,
                               const float* __restrict__ h, float* __restrict__ agg, int nE) {
    long long tid = (long long)blockIdx.x * blockDim.x + threadIdx.x;
    long long total = (long long)nE * F;
    if (tid >= total) return;
    int e = (int)(tid / F);
    int f = (int)(tid % F);
    int s = src[e];
    int d = dst[e];
    atomicAdd(&agg[(size_t)d * F + f], h[(size_t)s * F + f]);
}

// ---------------- node update: hout = [relu](mean @ Wl + bl + hin @ Wr) ----------------
template <int IN, bool RELU>
__global__ void node_update(const float* __restrict__ agg, const float* __restrict__ deg,
                            const float* __restrict__ hin,
                            const float* __restrict__ Wl, const float* __restrict__ bl,
                            const float* __restrict__ Wr,
                            float* __restrict__ hout, int n) {
    int i = blockIdx.x * blockDim.x + threadIdx.x;
    if (i >= n) return;
    float rdeg = 1.0f / fmaxf(deg[i], 1.0f);
    float acc[HID];
#pragma unroll
    for (int j = 0; j < HID; ++j) acc[j] = bl[j];
    const float* ag = agg + (size_t)i * IN;
    const float* hi = hin + (size_t)i * IN;
    for (int k = 0; k < IN; ++k) {
        float mk = ag[k] * rdeg;
        float xk = hi[k];
        const float* wl = Wl + (size_t)k * HID;
        const float* wr = Wr + (size_t)k * HID;
#pragma unroll
        for (int j = 0; j < HID; ++j) {
            float a = fmaf(mk, wl[j], acc[j]);
            acc[j] = fmaf(xk, wr[j], a);
        }
    }
    float* ho = hout + (size_t)i * HID;
#pragma unroll
    for (int j = 0; j < HID; ++j) {
        float v = acc[j];
        if (RELU) v = fmaxf(v, 0.0f);
        ho[j] = v;
    }
}

// ---------------- edge MLP: sigmoid(relu(relu([hs,hd,ea]@W1+b1)@W2+b2)@W3+b3) ----------------
__global__ void edge_mlp(const int* __restrict__ src, const int* __restrict__ dst,
                         const float* __restrict__ h, const float* __restrict__ ea,
                         const float* __restrict__ W1, const float* __restrict__ b1,
                         const float* __restrict__ W2, const float* __restrict__ b2,
                         const float* __restrict__ W3, const float* __restrict__ b3,
                         float* __restrict__ out, int nE) {
    int e = blockIdx.x * blockDim.x + threadIdx.x;
    if (e >= nE) return;
    int s = src[e];
    int d = dst[e];
    const float* hs = h + (size_t)s * HID;
    const float* hd = h + (size_t)d * HID;
    const float4* eav = (const float4*)(ea + (size_t)e * 8);

    float z1[64];
#pragma unroll
    for (int j = 0; j < 64; ++j) z1[j] = b1[j];

    // rows 0..63 of W1: h[src]
    for (int k0 = 0; k0 < 64; k0 += 4) {
        float4 v = *(const float4*)(hs + k0);
        const float* w = W1 + (size_t)k0 * 64;
#pragma unroll
        for (int j = 0; j < 64; ++j) {
            float a = fmaf(v.x, w[j], z1[j]);
            a = fmaf(v.y, w[64 + j], a);
            a = fmaf(v.z, w[128 + j], a);
            z1[j] = fmaf(v.w, w[192 + j], a);
        }
    }
    // rows 64..127 of W1: h[dst]
    for (int k0 = 0; k0 < 64; k0 += 4) {
        float4 v = *(const float4*)(hd + k0);
        const float* w = W1 + (size_t)(64 + k0) * 64;
#pragma unroll
        for (int j = 0; j < 64; ++j) {
            float a = fmaf(v.x, w[j], z1[j]);
            a = fmaf(v.y, w[64 + j], a);
            a = fmaf(v.z, w[128 + j], a);
            z1[j] = fmaf(v.w, w[192 + j], a);
        }
    }
    // rows 128..135 of W1: edge_attr
    {
        float4 v0 = eav[0];
        float4 v1 = eav[1];
        const float* w = W1 + (size_t)128 * 64;
#pragma unroll
        for (int j = 0; j < 64; ++j) {
            float a = fmaf(v0.x, w[j], z1[j]);
            a = fmaf(v0.y, w[64 + j], a);
            a = fmaf(v0.z, w[128 + j], a);
            a = fmaf(v0.w, w[192 + j], a);
            a = fmaf(v1.x, w[256 + j], a);
            a = fmaf(v1.y, w[320 + j], a);
            a = fmaf(v1.z, w[384 + j], a);
            z1[j] = fmaf(v1.w, w[448 + j], a);
        }
    }

    float z2[32];
#pragma unroll
    for (int j = 0; j < 32; ++j) z2[j] = b2[j];
    for (int k = 0; k < 64; ++k) {
        float v = fmaxf(z1[k], 0.0f);
        const float* w = W2 + (size_t)k * 32;
#pragma unroll
        for (int j = 0; j < 32; ++j) z2[j] = fmaf(v, w[j], z2[j]);
    }

    float o = b3[0];
#pragma unroll
    for (int k = 0; k < 32; ++k) o = fmaf(fmaxf(z2[k], 0.0f), W3[k], o);

    out[e] = 1.0f / (1.0f + __expf(-o));
}

extern "C" void kernel_launch(void* const* d_in, const int* in_sizes, int n_in,
                              void* d_out, int out_size, void* d_ws, size_t ws_size,
                              hipStream_t stream) {
    const float* x   = (const float*)d_in[0];
    const int*   ei  = (const int*)d_in[1];
    const float* ea  = (const float*)d_in[2];
    const float* Wl0 = (const float*)d_in[3];
    const float* bl0 = (const float*)d_in[4];
    const float* Wr0 = (const float*)d_in[5];
    const float* Wl1 = (const float*)d_in[6];
    const float* bl1 = (const float*)d_in[7];
    const float* Wr1 = (const float*)d_in[8];
    const float* Wl2 = (const float*)d_in[9];
    const float* bl2 = (const float*)d_in[10];
    const float* Wr2 = (const float*)d_in[11];
    const float* W1  = (const float*)d_in[12];
    const float* b1  = (const float*)d_in[13];
    const float* W2  = (const float*)d_in[14];
    const float* b2  = (const float*)d_in[15];
    const float* W3  = (const float*)d_in[16];
    const float* b3  = (const float*)d_in[17];

    const int* src = ei;
    const int* dst = ei + NE;

    float* agg = (float*)d_ws;                    // NN*64
    float* deg = agg + (size_t)NN * HID;          // NN
    float* hA  = deg + NN;                        // NN*64
    float* hB  = hA + (size_t)NN * HID;           // NN*64
    float* out = (float*)d_out;

    const int BS = 256;
    dim3 blkE((NE + BS - 1) / BS);
    dim3 blkN((NN + BS - 1) / BS);
    dim3 blkS32((int)(((long long)NE * 32 + BS - 1) / BS));
    dim3 blkS64((int)(((long long)NE * 64 + BS - 1) / BS));

    // layer 0 (IN=32)
    hipMemsetAsync(agg, 0, (size_t)NN * (HID + 1) * sizeof(float), stream);  // agg + deg
    deg_kernel<<<blkE, BS, 0, stream>>>(dst, deg, NE);
    scatter_kernel<32><<<blkS32, BS, 0, stream>>>(src, dst, x, agg, NE);
    node_update<32, true><<<blkN, BS, 0, stream>>>(agg, deg, x, Wl0, bl0, Wr0, hA, NN);

    // layer 1 (IN=64)
    hipMemsetAsync(agg, 0, (size_t)NN * HID * sizeof(float), stream);
    scatter_kernel<64><<<blkS64, BS, 0, stream>>>(src, dst, hA, agg, NE);
    node_update<64, true><<<blkN, BS, 0, stream>>>(agg, deg, hA, Wl1, bl1, Wr1, hB, NN);

    // layer 2 (IN=64, no relu)
    hipMemsetAsync(agg, 0, (size_t)NN * HID * sizeof(float), stream);
    scatter_kernel<64><<<blkS64, BS, 0, stream>>>(src, dst, hB, agg, NE);
    node_update<64, false><<<blkN, BS, 0, stream>>>(agg, deg, hB, Wl2, bl2, Wr2, hA, NN);

    // edge predictor
    edge_mlp<<<blkE, BS, 0, stream>>>(src, dst, hA, ea, W1, b1, W2, b2, W3, b3, out, NE);
}

// Round 2
// 852.809 us; speedup vs baseline: 2.1158x; 2.1158x over previous
//
#include <hip/hip_runtime.h>
#include <hip/hip_bf16.h>

#define NN 100000
#define NE 1600000
#define HID 64
#define SCAN_BS 256
#define NBLK ((NN + SCAN_BS - 1) / SCAN_BS)   // 391

// ---------- CSR build ----------
__global__ void count_kernel(const int* __restrict__ dst, int* __restrict__ degI, int nE) {
    int e = blockIdx.x * blockDim.x + threadIdx.x;
    if (e < nE) atomicAdd(&degI[dst[e]], 1);
}

__global__ void scan1_kernel(const int* __restrict__ degI, int* __restrict__ rowtmp,
                             int* __restrict__ blockSum) {
    __shared__ int tmp[SCAN_BS];
    int t = threadIdx.x;
    int i = blockIdx.x * SCAN_BS + t;
    int d = (i < NN) ? degI[i] : 0;
    tmp[t] = d;
    __syncthreads();
    for (int off = 1; off < SCAN_BS; off <<= 1) {
        int v = (t >= off) ? tmp[t - off] : 0;
        __syncthreads();
        tmp[t] += v;
        __syncthreads();
    }
    if (i < NN) rowtmp[i] = tmp[t] - d;           // exclusive within block
    if (t == SCAN_BS - 1) blockSum[blockIdx.x] = tmp[t];
}

__global__ void scan2_kernel(const int* __restrict__ blockSum, int* __restrict__ blockOff, int n) {
    __shared__ int tmp[512];
    int t = threadIdx.x;                          // 512 threads
    tmp[t] = (t < n) ? blockSum[t] : 0;
    __syncthreads();
    for (int off = 1; off < 512; off <<= 1) {
        int v = (t >= off) ? tmp[t - off] : 0;
        __syncthreads();
        tmp[t] += v;
        __syncthreads();
    }
    if (t < n) blockOff[t] = (t == 0) ? 0 : tmp[t - 1];
}

__global__ void scan3_kernel(const int* __restrict__ rowtmp, const int* __restrict__ blockOff,
                             int* __restrict__ row_ptr) {
    int i = blockIdx.x * SCAN_BS + threadIdx.x;
    if (i < NN) row_ptr[i] = rowtmp[i] + blockOff[blockIdx.x];
}

__global__ void fill_kernel(const int* __restrict__ src, const int* __restrict__ dst,
                            const int* __restrict__ row_ptr, int* __restrict__ cursor,
                            int* __restrict__ csr_src, int nE) {
    int e = blockIdx.x * blockDim.x + threadIdx.x;
    if (e >= nE) return;
    int d = dst[e];
    int pos = atomicAdd(&cursor[d], 1);
    csr_src[row_ptr[d] + pos] = src[e];
}

// ---------- fused SAGE layer: pull-aggregate + mean + dual matmul ----------
template <int IN, bool RELU>
__launch_bounds__(256)
__global__ void sage_layer(const int* __restrict__ row_ptr, const int* __restrict__ degI,
                           const int* __restrict__ csr_src,
                           const float* __restrict__ hin,
                           const float* __restrict__ Wl, const float* __restrict__ bl,
                           const float* __restrict__ Wr,
                           float* __restrict__ hout) {
    constexpr int SPLIT = 64 / IN;                // 2 for IN=32, 1 for IN=64
    int g = threadIdx.x >> 6;                     // node group within block (0..3)
    int lane = threadIdx.x & 63;
    int node = blockIdx.x * 4 + g;
    bool valid = node < NN;
    int f = lane & (IN - 1);
    int half = lane / IN;

    __shared__ float part[4][64];
    __shared__ float sh[4][IN];

    float acc = 0.f;
    int dg = 0;
    if (valid) {
        int start = row_ptr[node];
        dg = degI[node];
        const int* cs = csr_src + start;
        int e = half;
        for (; e + 3 * SPLIT < dg; e += 4 * SPLIT) {
            int s0 = cs[e], s1 = cs[e + SPLIT], s2 = cs[e + 2 * SPLIT], s3 = cs[e + 3 * SPLIT];
            float v0 = hin[(size_t)s0 * IN + f];
            float v1 = hin[(size_t)s1 * IN + f];
            float v2 = hin[(size_t)s2 * IN + f];
            float v3 = hin[(size_t)s3 * IN + f];
            acc += (v0 + v1) + (v2 + v3);
        }
        for (; e < dg; e += SPLIT) acc += hin[(size_t)cs[e] * IN + f];
        if (half == 0) sh[g][f] = hin[(size_t)node * IN + f];
    }
    part[g][lane] = acc;
    __syncthreads();

    if (valid) {
        float rdeg = 1.0f / fmaxf((float)dg, 1.0f);
        int j = lane;
        float oL = 0.f, oR = 0.f;
#pragma unroll
        for (int k = 0; k < IN; ++k) {
            float m = part[g][k];
            if (SPLIT == 2) m += part[g][k + 32];
            oL = fmaf(m, Wl[k * 64 + j], oL);
            oR = fmaf(sh[g][k], Wr[k * 64 + j], oR);
        }
        float o = bl[j] + oL * rdeg + oR;
        if (RELU) o = fmaxf(o, 0.f);
        hout[(size_t)node * 64 + j] = o;
    }
}

// ---------- per-node precompute of edge-MLP first layer (bf16 output) ----------
__launch_bounds__(256)
__global__ void precompute_a(const float* __restrict__ h, const float* __restrict__ W1,
                             __hip_bfloat16* __restrict__ a1, __hip_bfloat16* __restrict__ a2) {
    int g = threadIdx.x >> 6;
    int j = threadIdx.x & 63;
    int node = blockIdx.x * 4 + g;
    __shared__ float sh[4][64];
    if (node < NN) sh[g][j] = h[(size_t)node * 64 + j];
    __syncthreads();
    if (node >= NN) return;
    float acc1 = 0.f, acc2 = 0.f;
#pragma unroll
    for (int k = 0; k < 64; ++k) {
        float hv = sh[g][k];
        acc1 = fmaf(hv, W1[k * 64 + j], acc1);
        acc2 = fmaf(hv, W1[(64 + k) * 64 + j], acc2);
    }
    a1[(size_t)node * 64 + j] = (__hip_bfloat16)acc1;
    a2[(size_t)node * 64 + j] = (__hip_bfloat16)acc2;
}

// ---------- edge predictor ----------
__device__ __forceinline__ float bflo(unsigned u) { return __uint_as_float(u << 16); }
__device__ __forceinline__ float bfhi(unsigned u) { return __uint_as_float(u & 0xffff0000u); }

__launch_bounds__(256)
__global__ void edge_pred(const int* __restrict__ src, const int* __restrict__ dst,
                          const __hip_bfloat16* __restrict__ a1, const __hip_bfloat16* __restrict__ a2,
                          const float* __restrict__ ea,
                          const float* __restrict__ W1, const float* __restrict__ b1,
                          const float* __restrict__ W2, const float* __restrict__ b2,
                          const float* __restrict__ W3, const float* __restrict__ b3,
                          float* __restrict__ out, int nE) {
    int e = blockIdx.x * blockDim.x + threadIdx.x;
    if (e >= nE) return;
    int s = src[e];
    int d = dst[e];

    const uint4* pa = (const uint4*)(a1 + (size_t)s * 64);  // 8 × 16B
    const uint4* pb = (const uint4*)(a2 + (size_t)d * 64);
    const float4* eav = (const float4*)(ea + (size_t)e * 8);
    float4 v0 = eav[0];
    float4 v1 = eav[1];

    float z1[64];
    const float* wr = W1 + 128 * 64;
#pragma unroll
    for (int j = 0; j < 64; ++j) {
        float a = fmaf(v0.x, wr[j], b1[j]);
        a = fmaf(v0.y, wr[64 + j], a);
        a = fmaf(v0.z, wr[128 + j], a);
        a = fmaf(v0.w, wr[192 + j], a);
        a = fmaf(v1.x, wr[256 + j], a);
        a = fmaf(v1.y, wr[320 + j], a);
        a = fmaf(v1.z, wr[384 + j], a);
        z1[j] = fmaf(v1.w, wr[448 + j], a);
    }

#pragma unroll
    for (int q = 0; q < 8; ++q) {
        uint4 ua = pa[q];
        uint4 ub = pb[q];
        int j0 = q * 8;
        z1[j0 + 0] += bflo(ua.x) + bflo(ub.x);
        z1[j0 + 1] += bfhi(ua.x) + bfhi(ub.x);
        z1[j0 + 2] += bflo(ua.y) + bflo(ub.y);
        z1[j0 + 3] += bfhi(ua.y) + bfhi(ub.y);
        z1[j0 + 4] += bflo(ua.z) + bflo(ub.z);
        z1[j0 + 5] += bfhi(ua.z) + bfhi(ub.z);
        z1[j0 + 6] += bflo(ua.w) + bflo(ub.w);
        z1[j0 + 7] += bfhi(ua.w) + bfhi(ub.w);
    }

    float z2[32];
#pragma unroll
    for (int j = 0; j < 32; ++j) z2[j] = b2[j];
    for (int k = 0; k < 64; ++k) {
        float v = fmaxf(z1[k], 0.0f);
        const float* w = W2 + (size_t)k * 32;
#pragma unroll
        for (int j = 0; j < 32; ++j) z2[j] = fmaf(v, w[j], z2[j]);
    }

    float o = b3[0];
#pragma unroll
    for (int k = 0; k < 32; ++k) o = fmaf(fmaxf(z2[k], 0.0f), W3[k], o);

    out[e] = 1.0f / (1.0f + __expf(-o));
}

extern "C" void kernel_launch(void* const* d_in, const int* in_sizes, int n_in,
                              void* d_out, int out_size, void* d_ws, size_t ws_size,
                              hipStream_t stream) {
    const float* x   = (const float*)d_in[0];
    const int*   ei  = (const int*)d_in[1];
    const float* ea  = (const float*)d_in[2];
    const float* Wl0 = (const float*)d_in[3];
    const float* bl0 = (const float*)d_in[4];
    const float* Wr0 = (const float*)d_in[5];
    const float* Wl1 = (const float*)d_in[6];
    const float* bl1 = (const float*)d_in[7];
    const float* Wr1 = (const float*)d_in[8];
    const float* Wl2 = (const float*)d_in[9];
    const float* bl2 = (const float*)d_in[10];
    const float* Wr2 = (const float*)d_in[11];
    const float* W1  = (const float*)d_in[12];
    const float* b1  = (const float*)d_in[13];
    const float* W2  = (const float*)d_in[14];
    const float* b2  = (const float*)d_in[15];
    const float* W3  = (const float*)d_in[16];
    const float* b3  = (const float*)d_in[17];

    const int* src = ei;
    const int* dst = ei + NE;

    // workspace layout (all offsets 256B-aligned)
    char* ws = (char*)d_ws;
    size_t off = 0;
    auto alloc = [&](size_t bytes) {
        void* p = ws + off;
        off += (bytes + 255) & ~(size_t)255;
        return p;
    };
    float* hA = (float*)alloc((size_t)NN * HID * sizeof(float));
    float* hB = (float*)alloc((size_t)NN * HID * sizeof(float));
    __hip_bfloat16* a1 = (__hip_bfloat16*)alloc((size_t)NN * HID * sizeof(__hip_bfloat16));
    __hip_bfloat16* a2 = (__hip_bfloat16*)alloc((size_t)NN * HID * sizeof(__hip_bfloat16));
    int* degI    = (int*)alloc(NN * sizeof(int));
    int* row_ptr = (int*)alloc(NN * sizeof(int));
    int* rowtmp  = (int*)alloc(NN * sizeof(int));
    int* cursor  = (int*)alloc(NN * sizeof(int));
    int* blockSum= (int*)alloc(512 * sizeof(int));
    int* blockOff= (int*)alloc(512 * sizeof(int));
    int* csr_src = (int*)alloc((size_t)NE * sizeof(int));
    float* out = (float*)d_out;

    const int BS = 256;
    dim3 blkE((NE + BS - 1) / BS);
    dim3 blkN4((NN + 3) / 4);

    // ---- CSR build ----
    hipMemsetAsync(degI, 0, NN * sizeof(int), stream);
    hipMemsetAsync(cursor, 0, NN * sizeof(int), stream);
    count_kernel<<<blkE, BS, 0, stream>>>(dst, degI, NE);
    scan1_kernel<<<NBLK, SCAN_BS, 0, stream>>>(degI, rowtmp, blockSum);
    scan2_kernel<<<1, 512, 0, stream>>>(blockSum, blockOff, NBLK);
    scan3_kernel<<<NBLK, SCAN_BS, 0, stream>>>(rowtmp, blockOff, row_ptr);
    fill_kernel<<<blkE, BS, 0, stream>>>(src, dst, row_ptr, cursor, csr_src, NE);

    // ---- 3 SAGE layers (fused pull-aggregate + matmul) ----
    sage_layer<32, true ><<<blkN4, 256, 0, stream>>>(row_ptr, degI, csr_src, x,  Wl0, bl0, Wr0, hA);
    sage_layer<64, true ><<<blkN4, 256, 0, stream>>>(row_ptr, degI, csr_src, hA, Wl1, bl1, Wr1, hB);
    sage_layer<64, false><<<blkN4, 256, 0, stream>>>(row_ptr, degI, csr_src, hB, Wl2, bl2, Wr2, hA);

    // ---- edge predictor ----
    precompute_a<<<blkN4, 256, 0, stream>>>(hA, W1, a1, a2);
    edge_pred<<<blkE, BS, 0, stream>>>(src, dst, a1, a2, ea, W1, b1, W2, b2, W3, b3, out, NE);
}

// Round 3
// 781.607 us; speedup vs baseline: 2.3085x; 1.0911x over previous
//
#include <hip/hip_runtime.h>
#include <hip/hip_bf16.h>

#define NN 100000
#define NE 1600000
#define HID 64
#define SCAN_BS 256
#define NBLK ((NN + SCAN_BS - 1) / SCAN_BS)   // 391

__device__ __forceinline__ float bflo(unsigned u) { return __uint_as_float(u << 16); }
__device__ __forceinline__ float bfhi(unsigned u) { return __uint_as_float(u & 0xffff0000u); }
__device__ __forceinline__ unsigned short f2bf(float f) {
    __hip_bfloat16 h = (__hip_bfloat16)f;
    return *(unsigned short*)&h;
}

// ---------- x -> bf16 ----------
__global__ void xcast(const float* __restrict__ in, unsigned short* __restrict__ out, int n4) {
    int i = blockIdx.x * blockDim.x + threadIdx.x;
    if (i >= n4) return;
    float4 v = ((const float4*)in)[i];
    ushort4 o;
    o.x = f2bf(v.x); o.y = f2bf(v.y); o.z = f2bf(v.z); o.w = f2bf(v.w);
    ((ushort4*)out)[i] = o;
}

// ---------- CSR build ----------
__global__ void count_kernel(const int* __restrict__ dst, int* __restrict__ degI, int nE) {
    int e = blockIdx.x * blockDim.x + threadIdx.x;
    if (e < nE) atomicAdd(&degI[dst[e]], 1);
}

__global__ void scan1_kernel(const int* __restrict__ degI, int* __restrict__ rowtmp,
                             int* __restrict__ blockSum) {
    __shared__ int tmp[SCAN_BS];
    int t = threadIdx.x;
    int i = blockIdx.x * SCAN_BS + t;
    int d = (i < NN) ? degI[i] : 0;
    tmp[t] = d;
    __syncthreads();
    for (int off = 1; off < SCAN_BS; off <<= 1) {
        int v = (t >= off) ? tmp[t - off] : 0;
        __syncthreads();
        tmp[t] += v;
        __syncthreads();
    }
    if (i < NN) rowtmp[i] = tmp[t] - d;
    if (t == SCAN_BS - 1) blockSum[blockIdx.x] = tmp[t];
}

__global__ void scan2_kernel(const int* __restrict__ blockSum, int* __restrict__ blockOff, int n) {
    __shared__ int tmp[512];
    int t = threadIdx.x;
    tmp[t] = (t < n) ? blockSum[t] : 0;
    __syncthreads();
    for (int off = 1; off < 512; off <<= 1) {
        int v = (t >= off) ? tmp[t - off] : 0;
        __syncthreads();
        tmp[t] += v;
        __syncthreads();
    }
    if (t < n) blockOff[t] = (t == 0) ? 0 : tmp[t - 1];
}

__global__ void scan3_kernel(const int* __restrict__ rowtmp, const int* __restrict__ blockOff,
                             int* __restrict__ row_ptr) {
    int i = blockIdx.x * SCAN_BS + threadIdx.x;
    if (i < NN) row_ptr[i] = rowtmp[i] + blockOff[blockIdx.x];
}

__global__ void fill_kernel(const int* __restrict__ src, const int* __restrict__ dst,
                            const int* __restrict__ row_ptr, int* __restrict__ cursor,
                            int* __restrict__ csr_src, int nE) {
    int e = blockIdx.x * blockDim.x + threadIdx.x;
    if (e >= nE) return;
    int d = dst[e];
    int pos = atomicAdd(&cursor[d], 1);
    csr_src[row_ptr[d] + pos] = src[e];
}

// ---------- fused SAGE layer (bf16 in, bf16 out; LAST also emits a1/a2) ----------
// IN features per node; gather reads packed pairs (uint = 2 bf16).
// SPLIT = 128/IN edges concurrently in the wave.
template <int IN, bool RELU, bool LAST>
__launch_bounds__(256)
__global__ void sage_layer(const int* __restrict__ row_ptr, const int* __restrict__ degI,
                           const int* __restrict__ csr_src,
                           const unsigned short* __restrict__ hin,
                           const float* __restrict__ Wl, const float* __restrict__ bl,
                           const float* __restrict__ Wr,
                           unsigned short* __restrict__ hout,
                           const float* __restrict__ W1,
                           unsigned short* __restrict__ a1, unsigned short* __restrict__ a2) {
    constexpr int SPLIT = 128 / IN;               // 2 for IN=64, 4 for IN=32
    constexpr int PAIRS = IN / 2;
    int g = threadIdx.x >> 6;
    int lane = threadIdx.x & 63;
    int node = blockIdx.x * 4 + g;
    bool valid = node < NN;
    int lane_p = lane & (PAIRS - 1);              // feature-pair index
    int sub = lane / PAIRS;                       // edge slot 0..SPLIT-1

    __shared__ float part[4][SPLIT * IN];
    __shared__ float sh[4][IN];
    __shared__ float sh2[4][64];                  // used only when LAST

    float2 acc = {0.f, 0.f};
    int dg = 0;
    if (valid) {
        int start = row_ptr[node];
        dg = degI[node];
        const int* cs = csr_src + start;
        int e = sub;
        for (; e + SPLIT * 3 < dg; e += SPLIT * 4) {
            int s0 = cs[e];
            int s1 = cs[e + SPLIT];
            int s2 = cs[e + SPLIT * 2];
            int s3 = cs[e + SPLIT * 3];
            unsigned u0 = *(const unsigned*)(hin + (size_t)s0 * IN + 2 * lane_p);
            unsigned u1 = *(const unsigned*)(hin + (size_t)s1 * IN + 2 * lane_p);
            unsigned u2 = *(const unsigned*)(hin + (size_t)s2 * IN + 2 * lane_p);
            unsigned u3 = *(const unsigned*)(hin + (size_t)s3 * IN + 2 * lane_p);
            acc.x += (bflo(u0) + bflo(u1)) + (bflo(u2) + bflo(u3));
            acc.y += (bfhi(u0) + bfhi(u1)) + (bfhi(u2) + bfhi(u3));
        }
        for (; e < dg; e += SPLIT) {
            unsigned u = *(const unsigned*)(hin + (size_t)cs[e] * IN + 2 * lane_p);
            acc.x += bflo(u);
            acc.y += bfhi(u);
        }
        if (sub == 0) {
            unsigned u = *(const unsigned*)(hin + (size_t)node * IN + 2 * lane_p);
            sh[g][2 * lane_p] = bflo(u);
            sh[g][2 * lane_p + 1] = bfhi(u);
        }
    }
    *(float2*)&part[g][sub * IN + 2 * lane_p] = acc;
    __syncthreads();

    float o = 0.f;
    int j = lane;
    if (valid) {
        float rdeg = 1.0f / fmaxf((float)dg, 1.0f);
        float oL = 0.f, oR = 0.f;
#pragma unroll
        for (int k = 0; k < IN; ++k) {
            float m = part[g][k];
#pragma unroll
            for (int s2 = 1; s2 < SPLIT; ++s2) m += part[g][s2 * IN + k];
            oL = fmaf(m, Wl[k * 64 + j], oL);
            oR = fmaf(sh[g][k], Wr[k * 64 + j], oR);
        }
        o = bl[j] + oL * rdeg + oR;
        if (RELU) o = fmaxf(o, 0.f);
        if (!LAST) hout[(size_t)node * 64 + j] = f2bf(o);
    }

    if (LAST) {
        if (valid) sh2[g][j] = o;
        __syncthreads();
        if (valid) {
            float A1 = 0.f, A2 = 0.f;
#pragma unroll
            for (int k = 0; k < 64; ++k) {
                float hv = sh2[g][k];
                A1 = fmaf(hv, W1[k * 64 + j], A1);
                A2 = fmaf(hv, W1[(64 + k) * 64 + j], A2);
            }
            a1[(size_t)node * 64 + j] = f2bf(A1);
            a2[(size_t)node * 64 + j] = f2bf(A2);
        }
    }
}

// ---------- edge predictor ----------
__launch_bounds__(256)
__global__ void edge_pred(const int* __restrict__ src, const int* __restrict__ dst,
                          const unsigned short* __restrict__ a1, const unsigned short* __restrict__ a2,
                          const float* __restrict__ ea,
                          const float* __restrict__ W1, const float* __restrict__ b1,
                          const float* __restrict__ W2, const float* __restrict__ b2,
                          const float* __restrict__ W3, const float* __restrict__ b3,
                          float* __restrict__ out, int nE) {
    int e = blockIdx.x * blockDim.x + threadIdx.x;
    if (e >= nE) return;
    int s = src[e];
    int d = dst[e];

    const uint4* pa = (const uint4*)(a1 + (size_t)s * 64);
    const uint4* pb = (const uint4*)(a2 + (size_t)d * 64);
    const float4* eav = (const float4*)(ea + (size_t)e * 8);
    float4 v0 = eav[0];
    float4 v1 = eav[1];

    float z1[64];
    const float* wr = W1 + 128 * 64;
#pragma unroll
    for (int j = 0; j < 64; ++j) {
        float a = fmaf(v0.x, wr[j], b1[j]);
        a = fmaf(v0.y, wr[64 + j], a);
        a = fmaf(v0.z, wr[128 + j], a);
        a = fmaf(v0.w, wr[192 + j], a);
        a = fmaf(v1.x, wr[256 + j], a);
        a = fmaf(v1.y, wr[320 + j], a);
        a = fmaf(v1.z, wr[384 + j], a);
        z1[j] = fmaf(v1.w, wr[448 + j], a);
    }

#pragma unroll
    for (int q = 0; q < 8; ++q) {
        uint4 ua = pa[q];
        uint4 ub = pb[q];
        int j0 = q * 8;
        z1[j0 + 0] += bflo(ua.x) + bflo(ub.x);
        z1[j0 + 1] += bfhi(ua.x) + bfhi(ub.x);
        z1[j0 + 2] += bflo(ua.y) + bflo(ub.y);
        z1[j0 + 3] += bfhi(ua.y) + bfhi(ub.y);
        z1[j0 + 4] += bflo(ua.z) + bflo(ub.z);
        z1[j0 + 5] += bfhi(ua.z) + bfhi(ub.z);
        z1[j0 + 6] += bflo(ua.w) + bflo(ub.w);
        z1[j0 + 7] += bfhi(ua.w) + bfhi(ub.w);
    }

    float z2[32];
#pragma unroll
    for (int j = 0; j < 32; ++j) z2[j] = b2[j];
    for (int k = 0; k < 64; ++k) {
        float v = fmaxf(z1[k], 0.0f);
        const float* w = W2 + (size_t)k * 32;
#pragma unroll
        for (int j = 0; j < 32; ++j) z2[j] = fmaf(v, w[j], z2[j]);
    }

    float o = b3[0];
#pragma unroll
    for (int k = 0; k < 32; ++k) o = fmaf(fmaxf(z2[k], 0.0f), W3[k], o);

    out[e] = 1.0f / (1.0f + __expf(-o));
}

extern "C" void kernel_launch(void* const* d_in, const int* in_sizes, int n_in,
                              void* d_out, int out_size, void* d_ws, size_t ws_size,
                              hipStream_t stream) {
    const float* x   = (const float*)d_in[0];
    const int*   ei  = (const int*)d_in[1];
    const float* ea  = (const float*)d_in[2];
    const float* Wl0 = (const float*)d_in[3];
    const float* bl0 = (const float*)d_in[4];
    const float* Wr0 = (const float*)d_in[5];
    const float* Wl1 = (const float*)d_in[6];
    const float* bl1 = (const float*)d_in[7];
    const float* Wr1 = (const float*)d_in[8];
    const float* Wl2 = (const float*)d_in[9];
    const float* bl2 = (const float*)d_in[10];
    const float* Wr2 = (const float*)d_in[11];
    const float* W1  = (const float*)d_in[12];
    const float* b1  = (const float*)d_in[13];
    const float* W2  = (const float*)d_in[14];
    const float* b2  = (const float*)d_in[15];
    const float* W3  = (const float*)d_in[16];
    const float* b3  = (const float*)d_in[17];

    const int* src = ei;
    const int* dst = ei + NE;

    char* ws = (char*)d_ws;
    size_t off = 0;
    auto alloc = [&](size_t bytes) {
        void* p = ws + off;
        off += (bytes + 255) & ~(size_t)255;
        return p;
    };
    unsigned short* xb = (unsigned short*)alloc((size_t)NN * 32 * 2);
    unsigned short* hA = (unsigned short*)alloc((size_t)NN * HID * 2);
    unsigned short* hB = (unsigned short*)alloc((size_t)NN * HID * 2);
    unsigned short* a1 = (unsigned short*)alloc((size_t)NN * HID * 2);
    unsigned short* a2 = (unsigned short*)alloc((size_t)NN * HID * 2);
    int* degI    = (int*)alloc(NN * sizeof(int));
    int* row_ptr = (int*)alloc(NN * sizeof(int));
    int* rowtmp  = (int*)alloc(NN * sizeof(int));
    int* cursor  = (int*)alloc(NN * sizeof(int));
    int* blockSum= (int*)alloc(512 * sizeof(int));
    int* blockOff= (int*)alloc(512 * sizeof(int));
    int* csr_src = (int*)alloc((size_t)NE * sizeof(int));
    float* out = (float*)d_out;

    const int BS = 256;
    dim3 blkE((NE + BS - 1) / BS);
    dim3 blkN4((NN + 3) / 4);
    int n4 = NN * 32 / 4;

    // ---- x -> bf16 + CSR build ----
    hipMemsetAsync(degI, 0, NN * sizeof(int), stream);
    hipMemsetAsync(cursor, 0, NN * sizeof(int), stream);
    xcast<<<(n4 + BS - 1) / BS, BS, 0, stream>>>(x, xb, n4);
    count_kernel<<<blkE, BS, 0, stream>>>(dst, degI, NE);
    scan1_kernel<<<NBLK, SCAN_BS, 0, stream>>>(degI, rowtmp, blockSum);
    scan2_kernel<<<1, 512, 0, stream>>>(blockSum, blockOff, NBLK);
    scan3_kernel<<<NBLK, SCAN_BS, 0, stream>>>(rowtmp, blockOff, row_ptr);
    fill_kernel<<<blkE, BS, 0, stream>>>(src, dst, row_ptr, cursor, csr_src, NE);

    // ---- 3 SAGE layers (fused pull-aggregate + matmul; last also emits a1/a2) ----
    sage_layer<32, true,  false><<<blkN4, 256, 0, stream>>>(row_ptr, degI, csr_src, xb, Wl0, bl0, Wr0, hA, nullptr, nullptr, nullptr);
    sage_layer<64, true,  false><<<blkN4, 256, 0, stream>>>(row_ptr, degI, csr_src, hA, Wl1, bl1, Wr1, hB, nullptr, nullptr, nullptr);
    sage_layer<64, false, true ><<<blkN4, 256, 0, stream>>>(row_ptr, degI, csr_src, hB, Wl2, bl2, Wr2, nullptr, W1, a1, a2);

    // ---- edge predictor ----
    edge_pred<<<blkE, BS, 0, stream>>>(src, dst, a1, a2, ea, W1, b1, W2, b2, W3, b3, out, NE);
}